// Round 7
// baseline (93.811 us; speedup 1.0000x reference)
//
#include <hip/hip_runtime.h>

#define THREADS 256
#define KNN 32
#define CAP 256
#define MAXRETRY 33

constexpr int Bc = 4, Nc = 8192, Sc = 2048, Cch = 64;

__device__ __forceinline__ unsigned dist2bits(float qx, float qy, float qz,
                                              float x, float y, float z) {
  // bit-exact vs numpy f32: no FMA contraction, fixed op order
  const float dx = __fsub_rn(qx, x);
  const float dy = __fsub_rn(qy, y);
  const float dz = __fsub_rn(qz, z);
  return __float_as_uint(__fadd_rn(
      __fadd_rn(__fmul_rn(dx, dx), __fmul_rn(dy, dy)), __fmul_rn(dz, dz)));
}

__global__ __launch_bounds__(THREADS, 4) void neighbor_group_kernel(
    const float* __restrict__ xyz,      // (B, N, 3)
    const float* __restrict__ new_xyz,  // (B, S, 3)
    const float* __restrict__ feat,     // (B, N, C)
    float* __restrict__ out)
{
  __shared__ uint4 keys4[Nc / 4];     // 32 KB: dist^2 bits for all points
  __shared__ unsigned candDb[CAP];
  __shared__ unsigned candIdx[CAP];
  __shared__ unsigned winIdx[KNN];
  __shared__ unsigned winDb[KNN];
  __shared__ unsigned wavePiv[4];
  __shared__ unsigned ccnt;

  const int tid  = threadIdx.x;
  const int lane = tid & 63;
  const int wid  = tid >> 6;
  const int q    = blockIdx.x;          // one query per block
  const int b    = q >> 11;             // / S (S = 2048)

  const float qx = new_xyz[q * 3 + 0];
  const float qy = new_xyz[q * 3 + 1];
  const float qz = new_xyz[q * 3 + 2];

  const float4* __restrict__ xb4 = (const float4*)(xyz + (size_t)b * Nc * 3);

  // ---- single distance pass: keys -> LDS (frees VGPRs so the 24 global
  //      loads can pipeline); track per-thread min in a register ----
  unsigned lmin = 0xFFFFFFFFu;
#pragma unroll
  for (int j2 = 0; j2 < 8; ++j2) {
    const int g = tid + j2 * THREADS;   // group of 4 consecutive points
    const float4 f0 = xb4[3 * g + 0];
    const float4 f1 = xb4[3 * g + 1];
    const float4 f2 = xb4[3 * g + 2];
    const unsigned k0 = dist2bits(qx, qy, qz, f0.x, f0.y, f0.z);
    const unsigned k1 = dist2bits(qx, qy, qz, f0.w, f1.x, f1.y);
    const unsigned k2 = dist2bits(qx, qy, qz, f1.z, f1.w, f2.x);
    const unsigned k3 = dist2bits(qx, qy, qz, f2.y, f2.z, f2.w);
    lmin = min(min(lmin, min(k0, k1)), min(k2, k3));
    keys4[g] = make_uint4(k0, k1, k2, k3);
  }

  // ---- per-wave 8th-smallest of 64 lane-mins via bitwise ballot select ----
  // largest P with count(lmin < P) < 8; pivot = P+1 -> >=8/wave -> >=32 block
  unsigned P = 0u;
#pragma unroll
  for (int bb = 30; bb >= 0; --bb) {
    const unsigned t = P | (1u << bb);
    if (__popcll(__ballot(lmin < t)) < 8) P = t;
  }
  if (lane == 0) wavePiv[wid] = P + 1u;
  if (tid == 0) ccnt = 0u;
  __syncthreads();

  unsigned piv = max(max(wavePiv[0], wavePiv[1]),
                     max(wavePiv[2], wavePiv[3]));

  // ---- compaction (LDS sweep); rare bisection retry on overflow ----
  unsigned C = 0;
  unsigned lo = 0u, hi = 0xFFFFFFFFu;
  bool force = false;
  for (int it = 0; it < MAXRETRY; ++it) {
#pragma unroll
    for (int j2 = 0; j2 < 8; ++j2) {
      const int g = tid + j2 * THREADS;
      const uint4 kk = keys4[g];
      const unsigned ks[4] = {kk.x, kk.y, kk.z, kk.w};
#pragma unroll
      for (int k = 0; k < 4; ++k) {
        if (ks[k] < piv) {
          const unsigned pos = atomicAdd(&ccnt, 1u);
          if (pos < CAP) {
            candDb[pos]  = ks[k];
            candIdx[pos] = (unsigned)(4 * g + k);
          }
        }
      }
    }
    __syncthreads();
    const unsigned c = ccnt;            // block-uniform
    if (force || (c >= KNN && c <= CAP)) { C = min(c, (unsigned)CAP); break; }
    if (c < KNN) lo = piv; else hi = piv;
    if (hi - lo <= 1u) { piv = hi; force = true; }
    else piv = lo + ((hi - lo) >> 1);
    __syncthreads();
    if (tid == 0) ccnt = 0u;
    __syncthreads();
  }

  // ---- sqrt only candidates (numpy ranks use sqrt f32 bits + idx ties) ----
  for (unsigned t = tid; t < C; t += THREADS)
    candDb[t] = __float_as_uint(__fsqrt_rn(__uint_as_float(candDb[t])));
  __syncthreads();

  // ---- exact rank by (sqrt bits, idx); C <= 256 -> 1 candidate/thread ----
  for (unsigned t = tid; t < C; t += THREADS) {
    const unsigned mdb = candDb[t];
    const unsigned mix = candIdx[t];
    unsigned rank = 0u;
    for (unsigned o = 0; o < C; ++o) {   // same addr across lanes -> broadcast
      const unsigned odb = candDb[o];
      const unsigned oix = candIdx[o];
      rank += (odb < mdb || (odb == mdb && oix < mix)) ? 1u : 0u;
    }
    if (rank < KNN) { winIdx[rank] = mix; winDb[rank] = mdb; }
  }
  __syncthreads();

  // ---- outputs (flat concat: nxyz | idxs | nfeat | values), all f32 ----
  float* out_nx = out;                                   // B*S*K*3
  float* out_id = out + (size_t)Bc * Sc * KNN * 3;       // B*S*K
  float* out_nf = out_id + (size_t)Bc * Sc * KNN;        // B*S*K*C
  float* out_sv = out_nf + (size_t)Bc * Sc * KNN * Cch;  // B*S*K

  const float* xb = xyz + (size_t)b * Nc * 3;
  const float4* fb4 = (const float4*)(feat + (size_t)b * Nc * Cch);

  if (tid < KNN) {
    out_id[(size_t)q * KNN + tid] = (float)winIdx[tid];
    out_sv[(size_t)q * KNN + tid] = __uint_as_float(winDb[tid]);
  }
  if (tid < KNN * 3) {
    const int w = tid / 3, c3 = tid % 3;
    out_nx[((size_t)q * KNN + w) * 3 + c3] = xb[(size_t)winIdx[w] * 3 + c3];
  }
  // feature gather: 32 winners x 16 float4 = 512 float4 -> 2 rounds;
  // issue both loads before both stores (ILP over scattered L2 reads)
  float4* onf4 = (float4*)(out_nf + (size_t)q * KNN * Cch);
  const int w0 = tid >> 4, c40 = tid & 15;
  const int w1 = (tid + THREADS) >> 4, c41 = tid & 15;
  const float4 v0 = fb4[(size_t)winIdx[w0] * 16 + c40];
  const float4 v1 = fb4[(size_t)winIdx[w1] * 16 + c41];
  onf4[w0 * 16 + c40] = v0;
  onf4[w1 * 16 + c41] = v1;
}

extern "C" void kernel_launch(void* const* d_in, const int* in_sizes, int n_in,
                              void* d_out, int out_size, void* d_ws, size_t ws_size,
                              hipStream_t stream) {
  const float* xyz     = (const float*)d_in[0];
  const float* new_xyz = (const float*)d_in[1];
  const float* feat    = (const float*)d_in[2];
  float* out = (float*)d_out;

  const int grid = Bc * Sc;  // 8192 blocks, 1 query each
  neighbor_group_kernel<<<grid, THREADS, 0, stream>>>(xyz, new_xyz, feat, out);
}